// Round 2
// baseline (1238.349 us; speedup 1.0000x reference)
//
#include <hip/hip_runtime.h>

typedef __bf16 bf16x8 __attribute__((ext_vector_type(8)));
typedef __bf16 bf16x4 __attribute__((ext_vector_type(4)));
typedef float  f32x4  __attribute__((ext_vector_type(4)));

#define CIN   320
#define APAD  328   // LDS row stride bf16: 656B/row, 16B-aligned, 2-way bank alias (free)
#define BROWS 48    // 4 atoms * 12 neighbors per block

// ---- runtime dtype detection: flags[0]=1 if float inputs are fp32, flags[1]=1 if idx is int64
__global__ void detect_kernel(const unsigned short* __restrict__ atom_h,
                              const unsigned* __restrict__ idx_w, int* __restrict__ flags)
{
    if (threadIdx.x == 0 && blockIdx.x == 0) {
        int f32 = 0;
        for (int i = 0; i < 256; ++i) {
            const int e = (atom_h[i] >> 7) & 0xFF;   // bf16-exponent view of each halfword
            if (e >= 134) f32 = 1;                   // |x|>=128: impossible for N(0,1) bf16
        }
        int i64 = 1;
        for (int i = 0; i < 64; ++i)
            if (idx_w[2 * i + 1] != 0) i64 = 0;      // int64 nonneg < 1e5 -> high dwords all 0
        flags[0] = f32;
        flags[1] = i64;
    }
}

// ---- canonicalize a float tensor to bf16 in ws (cvt if fp32, copy if already bf16)
__global__ __launch_bounds__(256) void convert_bf16(const void* __restrict__ src,
    __bf16* __restrict__ dst, long n8, const int* __restrict__ flags)
{
    const long t = (long)blockIdx.x * 256 + threadIdx.x;
    if (t >= n8) return;
    const long i = t * 8;
    if (flags[0]) {
        const float* s = (const float*)src;
        bf16x8 o;
#pragma unroll
        for (int j = 0; j < 8; ++j) o[j] = (__bf16)s[i + j];
        *(bf16x8*)&dst[i] = o;
    } else {
        *(uint4*)&dst[i] = *(const uint4*)((const char*)src + i * 2);
    }
}

// MODE 0 = stats only, 1 = stats + store gated bf16 to ws, 2 = apply (recompute)
template<int MODE>
__global__ __launch_bounds__(256) void gemm_conv(
    const __bf16* __restrict__ atomb, const void* __restrict__ nbrp,
    const void* __restrict__ idxp, const __bf16* __restrict__ Wb,
    const int* __restrict__ flags,
    float* __restrict__ stats1, const float* __restrict__ coef1,
    __bf16* __restrict__ gws, float* __restrict__ nsum)
{
    __shared__ __align__(16) __bf16 Alds[BROWS * APAD];
    __shared__ float sumbuf[512];

    const int tid = threadIdx.x;
    const int blk = blockIdx.x;
    const long rowbase = (long)blk * BROWS;
    const int  n0 = blk * 4;
    const int  isf32 = flags[0];
    const int  isi64 = flags[1];

    if (MODE == 2) { sumbuf[tid] = 0.f; sumbuf[tid + 256] = 0.f; }

    // ---- stage A = [self(128) | gather(128) | nbr(64)] into LDS as bf16 ----
    {
        const int c  = tid & 15;   // 16 chunks per 128-elem half
        const int rs = tid >> 4;   // 16 rows per iteration
#pragma unroll
        for (int it = 0; it < 3; ++it) {
            const int lr = rs + it * 16;
            const int nn = n0 + lr / 12;
            *(uint4*)&Alds[lr * APAD + c * 8] =
                *(const uint4*)&atomb[(long)nn * 128 + c * 8];
            const long r = rowbase + lr;
            const int j = isi64 ? (int)((const long long*)idxp)[r]
                                : ((const int*)idxp)[r];
            *(uint4*)&Alds[lr * APAD + 128 + c * 8] =
                *(const uint4*)&atomb[(long)j * 128 + c * 8];
        }
        if (isf32) {
            const float* nf = (const float*)nbrp;
#pragma unroll
            for (int it = 0; it < 3; ++it) {
                const int lr = rs + it * 16;
                f32x4 v = *(const f32x4*)&nf[(rowbase + lr) * 64 + c * 4];
                bf16x4 o;
#pragma unroll
                for (int j = 0; j < 4; ++j) o[j] = (__bf16)v[j];
                *(bf16x4*)&Alds[lr * APAD + 256 + c * 4] = o;
            }
        } else {
            const __bf16* nb = (const __bf16*)nbrp;
            const int c2  = tid & 7;
            const int rs2 = tid >> 3;
#pragma unroll
            for (int it = 0; it < 2; ++it) {
                const int lr = rs2 + it * 32;
                if (lr < BROWS)
                    *(uint4*)&Alds[lr * APAD + 256 + c2 * 8] =
                        *(const uint4*)&nb[(rowbase + lr) * 64 + c2 * 8];
            }
        }
    }
    __syncthreads();

    const int lane = tid & 63;
    const int wv   = tid >> 6;
    const int quad = lane >> 4;
    const int lrow = lane & 15;
    const int cb0  = wv * 32;   // wave owns filter cols [cb0,cb0+32) + core cols [128+cb0,...)

    f32x4 acc[3][4] = {};       // 3 row-tiles x {filt0,filt1,core0,core1}

    for (int k0 = 0; k0 < CIN; k0 += 32) {
        bf16x8 bfrag[4];
#pragma unroll
        for (int ct = 0; ct < 4; ++ct) {
            const int col = cb0 + ((ct & 1) ? 16 : 0) + ((ct & 2) ? 128 : 0) + lrow;
            bfrag[ct] = *(const bf16x8*)&Wb[col * CIN + k0 + quad * 8];
        }
#pragma unroll
        for (int rt = 0; rt < 3; ++rt) {
            bf16x8 afrag = *(const bf16x8*)&Alds[(rt * 16 + lrow) * APAD + k0 + quad * 8];
#pragma unroll
            for (int ct = 0; ct < 4; ++ct)
                acc[rt][ct] = __builtin_amdgcn_mfma_f32_16x16x32_bf16(
                                  afrag, bfrag[ct], acc[rt][ct], 0, 0, 0);
        }
    }

    if (MODE <= 1) {
        float* st = stats1 + (blk & 63) * 512;
#pragma unroll
        for (int ct = 0; ct < 4; ++ct) {
            float s = 0.f, ss = 0.f;
#pragma unroll
            for (int rt = 0; rt < 3; ++rt)
#pragma unroll
                for (int r = 0; r < 4; ++r) {
                    const float v = acc[rt][ct][r];
                    s += v; ss += v * v;
                }
            s += __shfl_xor(s, 16); ss += __shfl_xor(ss, 16);
            s += __shfl_xor(s, 32); ss += __shfl_xor(ss, 32);
            if (quad == 0) {
                const int col = cb0 + ((ct & 1) ? 16 : 0) + ((ct & 2) ? 128 : 0) + lrow;
                atomicAdd(&st[col], s);
                atomicAdd(&st[256 + col], ss);
            }
        }
        if (MODE == 1) {
#pragma unroll
            for (int rt = 0; rt < 3; ++rt) {
                const long grow = rowbase + rt * 16 + quad * 4;
#pragma unroll
                for (int ct = 0; ct < 4; ++ct) {
                    const int col = cb0 + ((ct & 1) ? 16 : 0) + ((ct & 2) ? 128 : 0) + lrow;
#pragma unroll
                    for (int r = 0; r < 4; ++r)
                        gws[(grow + r) * 256 + col] = (__bf16)acc[rt][ct][r];
                }
            }
        }
    } else {
        // bn1 affine + sigmoid(filter)*relu(core), reduce over m into LDS
#pragma unroll
        for (int p = 0; p < 2; ++p) {
            const int cF = cb0 + p * 16 + lrow;                 // 0..127
            const float aF = coef1[cF],       bF = coef1[256 + cF];
            const float aC = coef1[128 + cF], bC = coef1[384 + cF];
#pragma unroll
            for (int rt = 0; rt < 3; ++rt)
#pragma unroll
                for (int r = 0; r < 4; ++r) {
                    const float gF = aF * acc[rt][p][r] + bF;
                    const float gC = aC * acc[rt][p + 2][r] + bC;
                    const float val = (1.f / (1.f + __expf(-gF))) * fmaxf(gC, 0.f);
                    const int lr = rt * 16 + quad * 4 + r;
                    atomicAdd(&sumbuf[(lr / 12) * 128 + cF], val);
                }
        }
        __syncthreads();
#pragma unroll
        for (int e = tid; e < 512; e += 256)
            nsum[(long)(n0 + (e >> 7)) * 128 + (e & 127)] = sumbuf[e];
    }
}

__global__ void reduce_bn1(const float* __restrict__ stats1, const void* __restrict__ gamma,
                           const void* __restrict__ beta, float* __restrict__ coef1,
                           const int* __restrict__ flags)
{
    const int c = threadIdx.x;  // 256
    const int isf32 = flags[0];
    float s = 0.f, ss = 0.f;
    for (int b = 0; b < 64; ++b) { s += stats1[b * 512 + c]; ss += stats1[b * 512 + 256 + c]; }
    const float inv  = 1.f / 1200000.f;
    const float mean = s * inv;
    const float var  = ss * inv - mean * mean;
    const float g  = isf32 ? ((const float*)gamma)[c] : (float)((const __bf16*)gamma)[c];
    const float bb = isf32 ? ((const float*)beta)[c]  : (float)((const __bf16*)beta)[c];
    const float A = g * rsqrtf(var + 1e-5f);
    coef1[c]       = A;
    coef1[256 + c] = bb - A * mean;   // linear bias b cancels in BN1 (mean-subtracted)
}

// Path A: read materialized gated, bn1 affine + gate + M-sum
__global__ __launch_bounds__(256) void apply_gated(const __bf16* __restrict__ g,
    const float* __restrict__ coef1, float* __restrict__ nsum)
{
    const int tid  = threadIdx.x;
    const int nloc = tid >> 4;
    const int fc   = (tid & 15) * 8;
    const long n   = (long)blockIdx.x * 16 + nloc;
    float aF[8], bF[8], aC[8], bC[8];
#pragma unroll
    for (int j = 0; j < 8; ++j) {
        aF[j] = coef1[fc + j];       bF[j] = coef1[256 + fc + j];
        aC[j] = coef1[128 + fc + j]; bC[j] = coef1[384 + fc + j];
    }
    float s[8] = {};
    const __bf16* base = g + n * (12 * 256);
#pragma unroll
    for (int m = 0; m < 12; ++m) {
        bf16x8 vF = *(const bf16x8*)&base[m * 256 + fc];
        bf16x8 vC = *(const bf16x8*)&base[m * 256 + 128 + fc];
#pragma unroll
        for (int j = 0; j < 8; ++j) {
            const float gF = aF[j] * (float)vF[j] + bF[j];
            const float gC = aC[j] * (float)vC[j] + bC[j];
            s[j] += (1.f / (1.f + __expf(-gF))) * fmaxf(gC, 0.f);
        }
    }
    f32x4 s0 = {s[0], s[1], s[2], s[3]}, s1 = {s[4], s[5], s[6], s[7]};
    *(f32x4*)&nsum[n * 128 + fc]     = s0;
    *(f32x4*)&nsum[n * 128 + fc + 4] = s1;
}

__global__ __launch_bounds__(256) void bn2_stats(const float* __restrict__ nsum,
                                                 float* __restrict__ stats2)
{
    __shared__ float ls[256], lss[256];
    const int tid = threadIdx.x;
    float s = 0.f, ss = 0.f;
    const long stride = (long)gridDim.x * 256;   // multiple of 128
    for (long i = (long)blockIdx.x * 256 + tid; i < 12800000L; i += stride) {
        const float v = nsum[i]; s += v; ss += v * v;
    }
    ls[tid] = s; lss[tid] = ss;
    __syncthreads();
    if (tid < 128) {
        atomicAdd(&stats2[tid],       ls[tid] + ls[tid + 128]);
        atomicAdd(&stats2[128 + tid], lss[tid] + lss[tid + 128]);
    }
}

__global__ void reduce_bn2(const float* __restrict__ stats2, const void* __restrict__ gamma,
                           const void* __restrict__ beta, float* __restrict__ coef2,
                           const int* __restrict__ flags)
{
    const int c = threadIdx.x;  // 128
    const int isf32 = flags[0];
    const float inv  = 1.f / 100000.f;
    const float mean = stats2[c] * inv;
    const float var  = stats2[128 + c] * inv - mean * mean;
    const float g  = isf32 ? ((const float*)gamma)[c] : (float)((const __bf16*)gamma)[c];
    const float bb = isf32 ? ((const float*)beta)[c]  : (float)((const __bf16*)beta)[c];
    const float A = g * rsqrtf(var + 1e-5f);
    coef2[c]       = A;
    coef2[128 + c] = bb - A * mean;
}

__global__ __launch_bounds__(256) void final_out(const __bf16* __restrict__ atomb,
    const float* __restrict__ nsum, const float* __restrict__ coef2,
    void* __restrict__ outp, const int* __restrict__ flags)
{
    const long i = ((long)blockIdx.x * 256 + threadIdx.x) * 8;   // 6250*256*8 = 12.8M exact
    const int f0 = (int)(i & 127);
    bf16x8 a  = *(const bf16x8*)&atomb[i];
    f32x4  u0 = *(const f32x4*)&nsum[i];
    f32x4  u1 = *(const f32x4*)&nsum[i + 4];
    float v[8];
#pragma unroll
    for (int j = 0; j < 8; ++j) {
        const float A  = coef2[f0 + j];
        const float B  = coef2[128 + f0 + j];
        const float ns = (j < 4) ? u0[j] : u1[j - 4];
        v[j] = fmaxf((float)a[j] + A * ns + B, 0.f);
    }
    if (flags[0]) {
        float* o = (float*)outp;
        f32x4 w0 = {v[0], v[1], v[2], v[3]}, w1 = {v[4], v[5], v[6], v[7]};
        *(f32x4*)&o[i]     = w0;
        *(f32x4*)&o[i + 4] = w1;
    } else {
        __bf16* o = (__bf16*)outp;
        bf16x8 w;
#pragma unroll
        for (int j = 0; j < 8; ++j) w[j] = (__bf16)v[j];
        *(bf16x8*)&o[i] = w;
    }
}

extern "C" void kernel_launch(void* const* d_in, const int* in_sizes, int n_in,
                              void* d_out, int out_size, void* d_ws, size_t ws_size,
                              hipStream_t stream)
{
    const void* atom = d_in[0];
    const void* nbr  = d_in[1];
    const void* idxp = d_in[2];
    const void* W    = d_in[3];
    // d_in[4] = linear bias: cancels exactly inside BN1, unused
    const void* g1   = d_in[5];
    const void* b1   = d_in[6];
    const void* g2   = d_in[7];
    const void* b2   = d_in[8];

    char* ws = (char*)d_ws;
    int*    flags  = (int*)ws;                       // 16 B
    float*  stats1 = (float*)(ws + 1024);            // 64*512*4 = 131072
    float*  coef1  = (float*)(ws + 132096);          // 2048
    float*  stats2 = (float*)(ws + 134144);          // 1024
    float*  coef2  = (float*)(ws + 135168);          // 1024
    __bf16* atomb  = (__bf16*)(ws + 136192);         // 12.8M bf16 = 25,600,000
    __bf16* Wb     = (__bf16*)(ws + 25736192);       // 81920 bf16 = 163,840
    float*  nsum   = (float*)(ws + 25900032);        // 100000*128*4 = 51,200,000
    __bf16* gws    = (__bf16*)(ws + 77100032);       // 1.2M*256*2 = 614,400,000

    const size_t need_big = 77100032UL + 614400000UL;

    hipMemsetAsync(ws, 0, 136192, stream);           // zero flags + stats (ws poisoned 0xAA)
    detect_kernel<<<1, 64, 0, stream>>>((const unsigned short*)atom, (const unsigned*)idxp, flags);
    convert_bf16<<<6250, 256, 0, stream>>>(atom, atomb, 1600000L, flags);
    convert_bf16<<<40, 256, 0, stream>>>(W, Wb, 10240L, flags);

    if (ws_size >= need_big) {
        gemm_conv<1><<<25000, 256, 0, stream>>>(atomb, nbr, idxp, Wb, flags,
                                                stats1, nullptr, gws, nullptr);
        reduce_bn1<<<1, 256, 0, stream>>>(stats1, g1, b1, coef1, flags);
        apply_gated<<<6250, 256, 0, stream>>>(gws, coef1, nsum);
    } else {
        gemm_conv<0><<<25000, 256, 0, stream>>>(atomb, nbr, idxp, Wb, flags,
                                                stats1, nullptr, nullptr, nullptr);
        reduce_bn1<<<1, 256, 0, stream>>>(stats1, g1, b1, coef1, flags);
        gemm_conv<2><<<25000, 256, 0, stream>>>(atomb, nbr, idxp, Wb, flags,
                                                nullptr, coef1, nullptr, nsum);
    }
    bn2_stats<<<512, 256, 0, stream>>>(nsum, stats2);
    reduce_bn2<<<1, 128, 0, stream>>>(stats2, g2, b2, coef2, flags);
    final_out<<<6250, 256, 0, stream>>>(atomb, nsum, coef2, d_out, flags);
}

// Round 3
// 1065.274 us; speedup vs baseline: 1.1625x; 1.1625x over previous
//
#include <hip/hip_runtime.h>

typedef __bf16 bf16x8 __attribute__((ext_vector_type(8)));
typedef __bf16 bf16x4 __attribute__((ext_vector_type(4)));
typedef float  f32x4  __attribute__((ext_vector_type(4)));

#define CIN   320
#define APAD  328   // LDS A stride (bf16): 656B/row -> conflict-free-ish b128 reads
#define ROWS  96    // 8 atoms * 12 neighbors per block
#define SPAD  264   // epilogue repack stride (bf16)

// ---- runtime dtype detection (one wave): flags[0]=fp32 inputs, flags[1]=int64 idx
__global__ void detect_kernel(const unsigned short* __restrict__ atom_h,
                              const unsigned* __restrict__ idx_w, int* __restrict__ flags)
{
    const int lane = threadIdx.x;   // 64
    int f32 = 0;
    for (int i = lane; i < 256; i += 64) {
        const int e = (atom_h[i] >> 7) & 0xFF;   // bf16-exponent view of each halfword
        if (e >= 134) f32 = 1;                   // |x|>=128 impossible for N(0,1) bf16
    }
    const unsigned long long m32 = __ballot(f32);
    const int hi = (idx_w[2 * lane + 1] != 0) ? 1 : 0;
    const unsigned long long mhi = __ballot(hi); // int64 nonneg < 1e5 -> high dwords 0
    if (lane == 0) { flags[0] = m32 ? 1 : 0; flags[1] = mhi ? 0 : 1; }
}

// ---- canonicalize float tensor to bf16 in ws (cvt if fp32, copy if already bf16)
__global__ __launch_bounds__(256) void convert_bf16(const void* __restrict__ src,
    __bf16* __restrict__ dst, long n8, const int* __restrict__ flags)
{
    const long t = (long)blockIdx.x * 256 + threadIdx.x;
    if (t >= n8) return;
    const long i = t * 8;
    if (flags[0]) {
        const float* s = (const float*)src;
        bf16x8 o;
#pragma unroll
        for (int j = 0; j < 8; ++j) o[j] = (__bf16)s[i + j];
        *(bf16x8*)&dst[i] = o;
    } else {
        *(uint4*)&dst[i] = *(const uint4*)((const char*)src + i * 2);
    }
}

// MODE 0 = stats only, 1 = stats + store gated bf16 to ws, 2 = apply (recompute)
template<int MODE>
__global__ __launch_bounds__(256, 2) void gemm_conv(
    const __bf16* __restrict__ atomb, const void* __restrict__ nbrp,
    const void* __restrict__ idxp, const __bf16* __restrict__ Wb,
    const int* __restrict__ flags,
    float* __restrict__ stats1, const float* __restrict__ coef1,
    __bf16* __restrict__ gws, float* __restrict__ nsum)
{
    __shared__ __align__(16) char smem[ROWS * APAD * 2];   // 62,976 B
    __bf16* Alds = (__bf16*)smem;

    const int tid = threadIdx.x;
    const int blk = blockIdx.x;
    const long rowbase = (long)blk * ROWS;
    const int  n0 = blk * 8;
    const int  isf32 = flags[0];
    const int  isi64 = flags[1];

    // ---- stage A = [self(128) | gather(128) | nbr(64)] into LDS as bf16 ----
    {
        const int c  = tid & 15;   // 16 chunks of 16B per 128-elem half
        const int rs = tid >> 4;   // 16 rows per iteration
#pragma unroll
        for (int it = 0; it < 6; ++it) {
            const int lr = rs + it * 16;
            const int nn = n0 + lr / 12;
            *(uint4*)&Alds[lr * APAD + c * 8] =
                *(const uint4*)&atomb[(long)nn * 128 + c * 8];
            const long r = rowbase + lr;
            const int j = isi64 ? (int)((const long long*)idxp)[r]
                                : ((const int*)idxp)[r];
            *(uint4*)&Alds[lr * APAD + 128 + c * 8] =
                *(const uint4*)&atomb[(long)j * 128 + c * 8];
        }
        if (isf32) {
            const float* nf = (const float*)nbrp;
#pragma unroll
            for (int it = 0; it < 6; ++it) {
                const int lr = rs + it * 16;
                f32x4 v = *(const f32x4*)&nf[(rowbase + lr) * 64 + c * 4];
                bf16x4 o;
#pragma unroll
                for (int j = 0; j < 4; ++j) o[j] = (__bf16)v[j];
                *(bf16x4*)&Alds[lr * APAD + 256 + c * 4] = o;
            }
        } else {
            const __bf16* nb = (const __bf16*)nbrp;
            const int c2  = tid & 7;   // 8 chunks cover 64 bf16
            const int rs2 = tid >> 3;  // 32 rows per iteration
#pragma unroll
            for (int it = 0; it < 3; ++it) {
                const int lr = rs2 + it * 32;
                *(uint4*)&Alds[lr * APAD + 256 + c2 * 8] =
                    *(const uint4*)&nb[(rowbase + lr) * 64 + c2 * 8];
            }
        }
    }
    __syncthreads();

    const int lane = tid & 63;
    const int wv   = tid >> 6;
    const int quad = lane >> 4;
    const int lrow = lane & 15;
    const int cb0  = wv * 32;   // wave owns filter cols [cb0,cb0+32) + core cols [128+cb0,...)

    int cols[4];
    const __bf16* wp[4];
#pragma unroll
    for (int ct = 0; ct < 4; ++ct) {
        cols[ct] = cb0 + ((ct & 1) ? 16 : 0) + ((ct & 2) ? 128 : 0) + lrow;
        wp[ct] = Wb + (long)cols[ct] * CIN + quad * 8;
    }

    f32x4 acc[6][4] = {};       // 6 row-tiles x {filt0,filt1,core0,core1}
    bf16x8 bcur[4], bnxt[4];
#pragma unroll
    for (int ct = 0; ct < 4; ++ct) bcur[ct] = *(const bf16x8*)(wp[ct]);

#pragma unroll
    for (int kk = 0; kk < 10; ++kk) {
        const int k0 = kk * 32;
        if (kk < 9) {
#pragma unroll
            for (int ct = 0; ct < 4; ++ct)
                bnxt[ct] = *(const bf16x8*)(wp[ct] + k0 + 32);
        }
#pragma unroll
        for (int rt = 0; rt < 6; ++rt) {
            bf16x8 afrag = *(const bf16x8*)&Alds[(rt * 16 + lrow) * APAD + k0 + quad * 8];
#pragma unroll
            for (int ct = 0; ct < 4; ++ct)
                acc[rt][ct] = __builtin_amdgcn_mfma_f32_16x16x32_bf16(
                                  afrag, bcur[ct], acc[rt][ct], 0, 0, 0);
        }
        if (kk < 9) {
#pragma unroll
            for (int ct = 0; ct < 4; ++ct) bcur[ct] = bnxt[ct];
        }
    }

    if (MODE <= 1) {
        float* st = stats1 + (blk & 63) * 512;
#pragma unroll
        for (int ct = 0; ct < 4; ++ct) {
            float s = 0.f, ss = 0.f;
#pragma unroll
            for (int rt = 0; rt < 6; ++rt)
#pragma unroll
                for (int r = 0; r < 4; ++r) {
                    const float v = acc[rt][ct][r];
                    s += v; ss += v * v;
                }
            s += __shfl_xor(s, 16); ss += __shfl_xor(ss, 16);
            s += __shfl_xor(s, 32); ss += __shfl_xor(ss, 32);
            if (quad == 0) {
                atomicAdd(&st[cols[ct]], s);
                atomicAdd(&st[256 + cols[ct]], ss);
            }
        }
        if (MODE == 1) {
            __syncthreads();                     // done reading Alds
            __bf16* S = (__bf16*)smem;           // repack 96 x SPAD bf16 (50,688 B)
#pragma unroll
            for (int rt = 0; rt < 6; ++rt)
#pragma unroll
                for (int ct = 0; ct < 4; ++ct)
#pragma unroll
                    for (int r = 0; r < 4; ++r)
                        S[(rt * 16 + quad * 4 + r) * SPAD + cols[ct]] = (__bf16)acc[rt][ct][r];
            __syncthreads();
            const __bf16* Sr = (const __bf16*)smem;
            __bf16* dst = gws + rowbase * 256;   // 96*256 bf16 contiguous
#pragma unroll
            for (int it = 0; it < 12; ++it) {
                const int e = tid * 8 + it * 2048;
                *(bf16x8*)&dst[e] = *(const bf16x8*)&Sr[(e >> 8) * SPAD + (e & 255)];
            }
        }
    } else {
        // MODE 2: bn1 affine + sigmoid(filter)*relu(core), reduce over m in LDS
        __syncthreads();                         // done reading Alds
        float* sumbuf = (float*)smem;            // 8 atoms x 128 ch
#pragma unroll
        for (int e = tid; e < 1024; e += 256) sumbuf[e] = 0.f;
        __syncthreads();
#pragma unroll
        for (int p = 0; p < 2; ++p) {
            const int cF = cb0 + p * 16 + lrow;                 // 0..127
            const float aF = coef1[cF],       bF = coef1[256 + cF];
            const float aC = coef1[128 + cF], bC = coef1[384 + cF];
#pragma unroll
            for (int rt = 0; rt < 6; ++rt)
#pragma unroll
                for (int r = 0; r < 4; ++r) {
                    const float gF = aF * acc[rt][p][r] + bF;
                    const float gC = aC * acc[rt][p + 2][r] + bC;
                    const float val = (1.f / (1.f + __expf(-gF))) * fmaxf(gC, 0.f);
                    const int lr = rt * 16 + quad * 4 + r;
                    atomicAdd(&sumbuf[(lr / 12) * 128 + cF], val);
                }
        }
        __syncthreads();
#pragma unroll
        for (int e = tid; e < 1024; e += 256)
            nsum[(long)(n0 + (e >> 7)) * 128 + (e & 127)] = sumbuf[e];
    }
}

__global__ void reduce_bn1(const float* __restrict__ stats1, const void* __restrict__ gamma,
                           const void* __restrict__ beta, float* __restrict__ coef1,
                           const int* __restrict__ flags)
{
    const int c = threadIdx.x;  // 256
    const int isf32 = flags[0];
    float s = 0.f, ss = 0.f;
    for (int b = 0; b < 64; ++b) { s += stats1[b * 512 + c]; ss += stats1[b * 512 + 256 + c]; }
    const float inv  = 1.f / 1200000.f;
    const float mean = s * inv;
    const float var  = ss * inv - mean * mean;
    const float g  = isf32 ? ((const float*)gamma)[c] : (float)((const __bf16*)gamma)[c];
    const float bb = isf32 ? ((const float*)beta)[c]  : (float)((const __bf16*)beta)[c];
    const float A = g * rsqrtf(var + 1e-5f);
    coef1[c]       = A;
    coef1[256 + c] = bb - A * mean;   // linear bias b cancels in BN1 (mean-subtracted)
}

// Path A: read materialized gated, bn1 affine + gate + M-sum
__global__ __launch_bounds__(256) void apply_gated(const __bf16* __restrict__ g,
    const float* __restrict__ coef1, float* __restrict__ nsum)
{
    const int tid  = threadIdx.x;
    const int nloc = tid >> 4;
    const int fc   = (tid & 15) * 8;
    const long n   = (long)blockIdx.x * 16 + nloc;
    float aF[8], bF[8], aC[8], bC[8];
#pragma unroll
    for (int j = 0; j < 8; ++j) {
        aF[j] = coef1[fc + j];       bF[j] = coef1[256 + fc + j];
        aC[j] = coef1[128 + fc + j]; bC[j] = coef1[384 + fc + j];
    }
    float s[8] = {};
    const __bf16* base = g + n * (12 * 256);
#pragma unroll
    for (int m = 0; m < 12; ++m) {
        bf16x8 vF = *(const bf16x8*)&base[m * 256 + fc];
        bf16x8 vC = *(const bf16x8*)&base[m * 256 + 128 + fc];
#pragma unroll
        for (int j = 0; j < 8; ++j) {
            const float gF = aF[j] * (float)vF[j] + bF[j];
            const float gC = aC[j] * (float)vC[j] + bC[j];
            s[j] += (1.f / (1.f + __expf(-gF))) * fmaxf(gC, 0.f);
        }
    }
    f32x4 s0 = {s[0], s[1], s[2], s[3]}, s1 = {s[4], s[5], s[6], s[7]};
    *(f32x4*)&nsum[n * 128 + fc]     = s0;
    *(f32x4*)&nsum[n * 128 + fc + 4] = s1;
}

__global__ __launch_bounds__(256) void bn2_stats(const float* __restrict__ nsum,
                                                 float* __restrict__ stats2)
{
    __shared__ float ls[256], lss[256];
    const int tid = threadIdx.x;
    float s = 0.f, ss = 0.f;
    const long stride = (long)gridDim.x * 256;   // multiple of 128
    for (long i = (long)blockIdx.x * 256 + tid; i < 12800000L; i += stride) {
        const float v = nsum[i]; s += v; ss += v * v;
    }
    ls[tid] = s; lss[tid] = ss;
    __syncthreads();
    if (tid < 128) {
        atomicAdd(&stats2[tid],       ls[tid] + ls[tid + 128]);
        atomicAdd(&stats2[128 + tid], lss[tid] + lss[tid + 128]);
    }
}

__global__ void reduce_bn2(const float* __restrict__ stats2, const void* __restrict__ gamma,
                           const void* __restrict__ beta, float* __restrict__ coef2,
                           const int* __restrict__ flags)
{
    const int c = threadIdx.x;  // 128
    const int isf32 = flags[0];
    const float inv  = 1.f / 100000.f;
    const float mean = stats2[c] * inv;
    const float var  = stats2[128 + c] * inv - mean * mean;
    const float g  = isf32 ? ((const float*)gamma)[c] : (float)((const __bf16*)gamma)[c];
    const float bb = isf32 ? ((const float*)beta)[c]  : (float)((const __bf16*)beta)[c];
    const float A = g * rsqrtf(var + 1e-5f);
    coef2[c]       = A;
    coef2[128 + c] = bb - A * mean;
}

__global__ __launch_bounds__(256) void final_out(const __bf16* __restrict__ atomb,
    const float* __restrict__ nsum, const float* __restrict__ coef2,
    void* __restrict__ outp, const int* __restrict__ flags)
{
    const long i = ((long)blockIdx.x * 256 + threadIdx.x) * 8;   // 6250*256*8 = 12.8M exact
    const int f0 = (int)(i & 127);
    bf16x8 a  = *(const bf16x8*)&atomb[i];
    f32x4  u0 = *(const f32x4*)&nsum[i];
    f32x4  u1 = *(const f32x4*)&nsum[i + 4];
    float v[8];
#pragma unroll
    for (int j = 0; j < 8; ++j) {
        const float A  = coef2[f0 + j];
        const float B  = coef2[128 + f0 + j];
        const float ns = (j < 4) ? u0[j] : u1[j - 4];
        v[j] = fmaxf((float)a[j] + A * ns + B, 0.f);
    }
    if (flags[0]) {
        float* o = (float*)outp;
        f32x4 w0 = {v[0], v[1], v[2], v[3]}, w1 = {v[4], v[5], v[6], v[7]};
        *(f32x4*)&o[i]     = w0;
        *(f32x4*)&o[i + 4] = w1;
    } else {
        __bf16* o = (__bf16*)outp;
        bf16x8 w;
#pragma unroll
        for (int j = 0; j < 8; ++j) w[j] = (__bf16)v[j];
        *(bf16x8*)&o[i] = w;
    }
}

extern "C" void kernel_launch(void* const* d_in, const int* in_sizes, int n_in,
                              void* d_out, int out_size, void* d_ws, size_t ws_size,
                              hipStream_t stream)
{
    const void* atom = d_in[0];
    const void* nbr  = d_in[1];
    const void* idxp = d_in[2];
    const void* W    = d_in[3];
    // d_in[4] = linear bias: cancels exactly inside BN1, unused
    const void* g1   = d_in[5];
    const void* b1   = d_in[6];
    const void* g2   = d_in[7];
    const void* b2   = d_in[8];

    char* ws = (char*)d_ws;
    int*    flags  = (int*)ws;                       // 16 B
    float*  stats1 = (float*)(ws + 1024);            // 64*512*4 = 131072
    float*  coef1  = (float*)(ws + 132096);          // 2048
    float*  stats2 = (float*)(ws + 134144);          // 1024
    float*  coef2  = (float*)(ws + 135168);          // 1024
    __bf16* atomb  = (__bf16*)(ws + 136192);         // 12.8M bf16 = 25,600,000
    __bf16* Wb     = (__bf16*)(ws + 25736192);       // 81920 bf16 = 163,840
    float*  nsum   = (float*)(ws + 25900032);        // 100000*128*4 = 51,200,000
    __bf16* gws    = (__bf16*)(ws + 77100032);       // 1.2M*256*2 = 614,400,000

    const size_t need_big = 77100032UL + 614400000UL;

    hipMemsetAsync(ws, 0, 136192, stream);           // zero flags + stats (ws poisoned 0xAA)
    detect_kernel<<<1, 64, 0, stream>>>((const unsigned short*)atom, (const unsigned*)idxp, flags);
    convert_bf16<<<6250, 256, 0, stream>>>(atom, atomb, 1600000L, flags);
    convert_bf16<<<40, 256, 0, stream>>>(W, Wb, 10240L, flags);

    if (ws_size >= need_big) {
        gemm_conv<1><<<12500, 256, 0, stream>>>(atomb, nbr, idxp, Wb, flags,
                                                stats1, nullptr, gws, nullptr);
        reduce_bn1<<<1, 256, 0, stream>>>(stats1, g1, b1, coef1, flags);
        apply_gated<<<6250, 256, 0, stream>>>(gws, coef1, nsum);
    } else {
        gemm_conv<0><<<12500, 256, 0, stream>>>(atomb, nbr, idxp, Wb, flags,
                                                stats1, nullptr, nullptr, nullptr);
        reduce_bn1<<<1, 256, 0, stream>>>(stats1, g1, b1, coef1, flags);
        gemm_conv<2><<<12500, 256, 0, stream>>>(atomb, nbr, idxp, Wb, flags,
                                                nullptr, coef1, nullptr, nsum);
    }
    bn2_stats<<<512, 256, 0, stream>>>(nsum, stats2);
    reduce_bn2<<<1, 128, 0, stream>>>(stats2, g2, b2, coef2, flags);
    final_out<<<6250, 256, 0, stream>>>(atomb, nsum, coef2, d_out, flags);
}